// Round 7
// baseline (173.276 us; speedup 1.0000x reference)
//
#include <hip/hip_runtime.h>
#include <hip/hip_bf16.h>

typedef __attribute__((ext_vector_type(8))) __bf16 bf16x8;
typedef __attribute__((ext_vector_type(4))) float f32x4;
typedef unsigned long long ull;

#define NB 16
#define CIN 32
#define COUT 64
#define HW 224
#define HWHW (HW * HW)          // 50176
#define CHW (CIN * HW * HW)     // 1605632
#define WSLOTS 68               // staged px slots per wave (64 + halo + pad)
#define ROW_DW (WSLOTS * 16)    // 1088 dwords per row per wave
#define WAVE_DW (3 * ROW_DW)    // 3264 dwords per wave

__device__ __forceinline__ unsigned short f2bf(float f) {
    __hip_bfloat16 h = __float2bfloat16(f);
    return __builtin_bit_cast(unsigned short, h);
}

// Swizzled dword index within one wave-row: slot s (0..67), channel-pair c2 (0..15).
// unit' = (c2>>2) ^ ((s>>1)&3): writes cover all 32 banks 2-way (free),
// b128 reads cover 16 full slots uniformly (8 words/bank floor).
__device__ __forceinline__ int swz_widx(int s, int c2) {
    return s * 16 + ((((c2 >> 2) ^ ((s >> 1) & 3))) << 2) + (c2 & 3);
}

// ---- K1: weight OIHW fp32 -> wT[co][tap][cin] bf16 (64*9*32 = 18432) ----
__global__ void k_wxform(const float* __restrict__ w, unsigned short* __restrict__ wT) {
    int i = blockIdx.x * 256 + threadIdx.x;
    if (i >= COUT * 9 * CIN) return;
    int co = i / (9 * CIN);
    int r  = i % (9 * CIN);
    int tap = r / CIN;
    int c   = r % CIN;
    wT[i] = f2bf(w[(co * CIN + c) * 9 + tap]);
}

// ---- K2: fused conv, barrier-free. One block per (b,h); each of 4 waves
// stages its OWN 68-px slice of the 3 input rows into private LDS (bf16,
// swizzled), then MFMAs 64px x 64cout. No __syncthreads anywhere. ----
__global__ __launch_bounds__(256, 3)
void k_fused(const float* __restrict__ x, const unsigned short* __restrict__ wT,
             const float* __restrict__ bias, float* __restrict__ out) {
    __shared__ __align__(16) unsigned int lds[4 * WAVE_DW];   // 52224 B

    int bid = blockIdx.x;
    int wg  = (bid & 7) * 448 + (bid >> 3);   // XCD-chunked swizzle, 3584 = 8*448
    int b = wg / HW, h = wg % HW;
    int tid = threadIdx.x;
    int wave = tid >> 6, lane = tid & 63;
    int c4 = lane >> 4, p16 = lane & 15;

    unsigned int* wlds = lds + wave * WAVE_DW;
    const float* xb = x + (ull)b * CHW;
    int pxbase = wave * 64 - 1;               // global px of slot 0

    // ---- stage (per-wave private, no barrier) ----
    #pragma unroll
    for (int r3 = 0; r3 < 3; ++r3) {
        int hy = h + r3 - 1;
        bool vrow = ((unsigned)hy < (unsigned)HW);
        const float* xr = xb + (ull)(vrow ? hy : 0) * HW;
        unsigned int* rlds = wlds + r3 * ROW_DW;
        #pragma unroll
        for (int i = 0; i < 4; ++i) {         // slots 0..63: coalesced 64B loads
            int slot = i * 16 + p16;
            int px = pxbase + slot;
            bool v = vrow && ((unsigned)px < (unsigned)HW);
            const float* p = xr + px;
            #pragma unroll
            for (int j = 0; j < 4; ++j) {
                int c = 8 * j + 2 * c4;
                float f0 = v ? p[(ull)c * HWHW] : 0.f;
                float f1 = v ? p[(ull)(c + 1) * HWHW] : 0.f;
                rlds[swz_widx(slot, 4 * j + c4)] =
                    (unsigned)f2bf(f0) | ((unsigned)f2bf(f1) << 16);
            }
        }
        {                                     // remainder slots 64..67
            int slot = 64 + c4;
            int px = pxbase + slot;
            bool v = vrow && ((unsigned)px < (unsigned)HW);
            const float* p = xr + px;
            int c = 2 * p16;
            float f0 = v ? p[(ull)c * HWHW] : 0.f;
            float f1 = v ? p[(ull)(c + 1) * HWHW] : 0.f;
            rlds[swz_widx(slot, p16)] =
                (unsigned)f2bf(f0) | ((unsigned)f2bf(f1) << 16);
        }
    }

    // ---- compute (reads only this wave's LDS region; lgkmcnt orders it) ----
    int r15 = lane & 15;              // A-row (pixel local) / B-col (cout local)
    int q = lane >> 4;
    int chunk = q * 8;                // k sub-chunk (cin)

    int soff[4][3];                   // byte offsets within a wave-row
    #pragma unroll
    for (int pf = 0; pf < 4; ++pf)
        #pragma unroll
        for (int dw = 0; dw < 3; ++dw) {
            int s = pf * 16 + r15 + dw;       // 0..65, fully staged
            soff[pf][dw] = (s * 16 + ((q ^ ((s >> 1) & 3)) << 2)) * 4;
        }

    f32x4 acc[4][4];
    #pragma unroll
    for (int i = 0; i < 4; ++i)
        #pragma unroll
        for (int j = 0; j < 4; ++j) acc[i][j] = (f32x4){0.f, 0.f, 0.f, 0.f};

    const char* wldsc = reinterpret_cast<const char*>(wlds);
    #pragma unroll
    for (int r3 = 0; r3 < 3; ++r3) {
        const char* lrow = wldsc + r3 * (ROW_DW * 4);
        #pragma unroll
        for (int dw = 0; dw < 3; ++dw) {
            int tap = r3 * 3 + dw;
            bf16x8 wf[4], xf[4];
            #pragma unroll
            for (int cf = 0; cf < 4; ++cf)
                wf[cf] = *reinterpret_cast<const bf16x8*>(wT + (cf * 16 + r15) * 288 + tap * 32 + chunk);
            #pragma unroll
            for (int pf = 0; pf < 4; ++pf)
                xf[pf] = *reinterpret_cast<const bf16x8*>(lrow + soff[pf][dw]);
            #pragma unroll
            for (int cf = 0; cf < 4; ++cf)
                #pragma unroll
                for (int pf = 0; pf < 4; ++pf)
                    acc[cf][pf] = __builtin_amdgcn_mfma_f32_16x16x32_bf16(xf[pf], wf[cf], acc[cf][pf], 0, 0, 0);
        }
    }

    // epilogue: D row = pixel = q*4+reg, col = cout = lane&15; normal stores
    #pragma unroll
    for (int cf = 0; cf < 4; ++cf) {
        int co = cf * 16 + r15;
        float bv = bias[co];
        float* orow = out + ((ull)(b * COUT + co) * HW + h) * HW;
        #pragma unroll
        for (int pf = 0; pf < 4; ++pf) {
            int pxb = wave * 64 + pf * 16;
            if (pxb < HW) {                  // frag fully valid or fully masked
                int px0 = pxb + q * 4;
                *reinterpret_cast<f32x4*>(orow + px0) = acc[cf][pf] + bv;
            }
        }
    }
}

// ---- fallback: naive direct fp32 conv (used only if ws too small) ----
__global__ void k_naive(const float* __restrict__ x, const float* __restrict__ w,
                        const float* __restrict__ bias, float* __restrict__ out, long long n) {
    long long i = (long long)blockIdx.x * 256 + threadIdx.x;
    if (i >= n) return;
    int wc = i % HW; long long t = i / HW;
    int h = t % HW; t /= HW;
    int co = t % COUT; int b = (int)(t / COUT);
    float s = bias[co];
    for (int c = 0; c < CIN; ++c)
        for (int dh = 0; dh < 3; ++dh) {
            int hy = h + dh - 1; if (hy < 0 || hy >= HW) continue;
            for (int dw = 0; dw < 3; ++dw) {
                int wx = wc + dw - 1; if (wx < 0 || wx >= HW) continue;
                s += x[(((long long)b * CIN + c) * HW + hy) * HW + wx] *
                     w[((co * CIN + c) * 3 + dh) * 3 + dw];
            }
        }
    out[i] = s;
}

extern "C" void kernel_launch(void* const* d_in, const int* in_sizes, int n_in,
                              void* d_out, int out_size, void* d_ws, size_t ws_size,
                              hipStream_t stream) {
    const float* x    = (const float*)d_in[0];
    const float* w    = (const float*)d_in[1];
    const float* bias = (const float*)d_in[2];
    float* out = (float*)d_out;

    if (ws_size < (size_t)(COUT * 9 * CIN * 2 + 1024)) {
        long long n = (long long)NB * COUT * HW * HW;
        k_naive<<<(int)((n + 255) / 256), 256, 0, stream>>>(x, w, bias, out, n);
        return;
    }
    unsigned short* wT = (unsigned short*)d_ws;

    k_wxform<<<72, 256, 0, stream>>>(w, wT);
    k_fused<<<NB * HW, 256, 0, stream>>>(x, wT, bias, out);
}